// Round 6
// baseline (560.560 us; speedup 1.0000x reference)
//
#include <hip/hip_runtime.h>
#include <stdint.h>

// Round 6: occupancy + parallelism, same 76.94 MB workspace.
//  k_bin: CHUNK=4096 (LDS 25.6 KB -> 6 blocks/CU vs 3), 16-event register
//         stash, classify once. pfx stored per GROUP of 4 buckets (600/row);
//         within-group bucket id carried in the payload (2 bits).
//  k_transpose: pfx [4096][600] -> pfxT [600][4096] so k_accum offset loads
//         are coalesced.
//  k_accum: TPB=512, one block per 4-bucket group (600 blocks, XCD-swizzled);
//         packed u64 LDS atomic per event (count @bit40 | wt_q22 sum @bit0).
//
// bucket = (dt*2+p)*300 + pos (2400); payload u32 = c<<30 | tok<<22 | wt_q22.
// t is sorted -> dt constant within a chunk -> spans are dense (~109 B).

#define TPB 256
#define B1 4096
#define CHUNK 4096                 // B1*CHUNK = 2^24 = n
#define EVT (CHUNK / TPB)          // 16 events per thread
#define NBUCKET 2400
#define SCAN_PER 10                // ceil(NBUCKET/TPB)
#define GACC 4                     // buckets per group
#define NG (NBUCKET / GACC)        // 600 groups
#define ATPB 512                   // k_accum block size

// ws bytes: payload u32*n (67,108,864) | pfx u16 [B1][NG] (4,915,200)
//           | pfxT u16 [NG][B1] (4,915,200)  = 76,939,264 (== round-5 need)

__device__ __forceinline__ void classify_full(const float4 e, const float t0,
                                              const float d_wt, const float d_dt,
                                              int& bucket, int& tok, float& wt) {
    const float c1 = (float)(319.0 / 20.0 + 1e-4);   // W/PW + B
    const float c2 = (float)(239.0 / 15.0 + 1e-4);   // H/PH + B
    const int pos = (int)(floorf(e.y / c1) + floorf(e.z / c2) * 20.0f);
    tok = (int)(floorf(fmodf(e.y, c1)) + floorf(fmodf(e.z, c2)) * 16.0f);
    const int dt = (int)floorf(4.0f * (e.x - t0) / d_dt);
    const int p  = (int)e.w;
    bucket = (dt * 2 + p) * 300 + pos;
    wt = (e.x - t0) / d_wt;
}

__global__ __launch_bounds__(TPB, 6) void k_bin(const float4* __restrict__ x,
                                                uint32_t* __restrict__ payload,
                                                uint16_t* __restrict__ pfx,
                                                int n) {
    __shared__ uint32_t stage[CHUNK];     // 16 KB
    __shared__ uint32_t cnt[NBUCKET];     // 9.6 KB: counts, then cursors
    __shared__ uint32_t wsum[TPB / 64];

    for (int i = threadIdx.x; i < NBUCKET; i += TPB) cnt[i] = 0;
    __syncthreads();

    const float* xf = (const float*)x;
    const float t0 = xf[0];
    const float tlast = xf[(size_t)(n - 1) * 4];
    const float d_wt = tlast - t0 + 1e-4f;
    const float d_dt = tlast - t0 + 1.0f;

    const int beg = blockIdx.x * CHUNK;
    const bool full = (beg + CHUNK <= n);

    // phase 1: classify once, stash payload+bucket in registers, count
    uint32_t pk[EVT];
    uint32_t bk[EVT];
    if (full) {
        #pragma unroll
        for (int k = 0; k < EVT; ++k) {
            float4 e = x[beg + threadIdx.x + k * TPB];
            int bucket, tok; float wt;
            classify_full(e, t0, d_wt, d_dt, bucket, tok, wt);
            uint32_t q = (uint32_t)(wt * 4194304.0f);          // q22
            q = q > 4194303u ? 4194303u : q;
            pk[k] = ((uint32_t)(bucket & 3) << 30) | ((uint32_t)tok << 22) | q;
            bk[k] = (uint32_t)bucket;
            atomicAdd(&cnt[bucket], 1u);
        }
    } else {
        #pragma unroll
        for (int k = 0; k < EVT; ++k) {
            const int i = beg + threadIdx.x + k * TPB;
            if (i < n) {
                float4 e = x[i];
                int bucket, tok; float wt;
                classify_full(e, t0, d_wt, d_dt, bucket, tok, wt);
                uint32_t q = (uint32_t)(wt * 4194304.0f);
                q = q > 4194303u ? 4194303u : q;
                pk[k] = ((uint32_t)(bucket & 3) << 30) | ((uint32_t)tok << 22) | q;
                bk[k] = (uint32_t)bucket;
                atomicAdd(&cnt[bucket], 1u);
            } else {
                bk[k] = 0xFFFFFFFFu;
            }
        }
    }
    __syncthreads();

    // phase 2: block-local exclusive scan of NBUCKET counts
    uint32_t v[SCAN_PER];
    uint32_t sum = 0;
    const int base_i = threadIdx.x * SCAN_PER;
    #pragma unroll
    for (int j = 0; j < SCAN_PER; ++j) {
        int idx = base_i + j;
        uint32_t c = (idx < NBUCKET) ? cnt[idx] : 0u;
        v[j] = sum;
        sum += c;
    }
    uint32_t inc = sum;
    #pragma unroll
    for (int off = 1; off < 64; off <<= 1) {
        uint32_t u = __shfl_up(inc, off, 64);
        if ((threadIdx.x & 63) >= off) inc += u;
    }
    const int wid = threadIdx.x >> 6, lid = threadIdx.x & 63;
    if (lid == 63) wsum[wid] = inc;
    __syncthreads();
    uint32_t woff = 0;
    for (int w = 0; w < wid; ++w) woff += wsum[w];
    const uint32_t excl = woff + inc - sum;

    uint16_t* prow = pfx + (size_t)blockIdx.x * NG;
    #pragma unroll
    for (int j = 0; j < SCAN_PER; ++j) {
        int idx = base_i + j;
        if (idx < NBUCKET) {
            uint32_t p = excl + v[j];
            cnt[idx] = p;                       // cursor for the sort
            if ((idx & 3) == 0) prow[idx >> 2] = (uint16_t)p;   // group start
        }
    }
    __syncthreads();

    // phase 3: replay from registers -> rank -> LDS stage
    if (full) {
        #pragma unroll
        for (int k = 0; k < EVT; ++k) {
            uint32_t rank = atomicAdd(&cnt[bk[k]], 1u);
            stage[rank] = pk[k];
        }
    } else {
        #pragma unroll
        for (int k = 0; k < EVT; ++k) {
            if (bk[k] != 0xFFFFFFFFu) {
                uint32_t rank = atomicAdd(&cnt[bk[k]], 1u);
                stage[rank] = pk[k];
            }
        }
    }
    __syncthreads();

    // phase 4: coalesced LDS -> global writeout (complete lines only)
    const int end = min(beg + CHUNK, n);
    const int cntE = end - beg;
    uint32_t* pbase = payload + (size_t)blockIdx.x * CHUNK;
    const int n4 = cntE >> 2;
    const uint4* s4 = (const uint4*)stage;
    uint4* g4 = (uint4*)pbase;
    for (int i = threadIdx.x; i < n4; i += TPB) g4[i] = s4[i];
    for (int i = (n4 << 2) + threadIdx.x; i < cntE; i += TPB) pbase[i] = stage[i];
}

// pfx [B1][NG] u16 -> pfxT [NG][B1] u16 (coalesced offset reads in k_accum)
__global__ __launch_bounds__(256) void k_transpose(const uint16_t* __restrict__ in,
                                                   uint16_t* __restrict__ out) {
    __shared__ uint16_t tile[32][33];
    const int c0 = blockIdx.x * 32;    // NG cols: 19 tiles (guarded, 600 not /32)
    const int r0 = blockIdx.y * 32;    // B1 rows: 128 tiles
    const int tx = threadIdx.x & 31;
    const int ty = threadIdx.x >> 5;   // 0..7
    for (int j = ty; j < 32; j += 8)
        if (c0 + tx < NG)
            tile[j][tx] = in[(size_t)(r0 + j) * NG + (c0 + tx)];
    __syncthreads();
    for (int j = ty; j < 32; j += 8)
        if (c0 + j < NG)
            out[(size_t)(c0 + j) * B1 + (r0 + tx)] = tile[tx][j];
}

// One block per 4-bucket group, XCD-swizzled (XCD k owns 75 adjacent groups
// = buckets [300k, 300k+300) -> boundary lines stay in one XCD L2).
__global__ __launch_bounds__(ATPB) void k_accum(const uint32_t* __restrict__ payload,
                                                const uint16_t* __restrict__ pfxT,
                                                float* __restrict__ out,
                                                int n) {
    __shared__ unsigned long long hist[GACC * 256];   // (c,tok) -> cnt<<40 | q22sum
    for (int i = threadIdx.x; i < GACC * 256; i += ATPB) hist[i] = 0ULL;
    __syncthreads();

    const int xcd = blockIdx.x & 7;
    const int slot = blockIdx.x >> 3;
    const int g = xcd * (NG / 8) + slot;
    const uint16_t* colb = pfxT + (size_t)g * B1;
    const uint16_t* cole = (g + 1 < NG) ? (pfxT + (size_t)(g + 1) * B1) : nullptr;

    for (int row = threadIdx.x; row < B1; row += ATPB) {
        const int sbeg = colb[row];
        int send;
        if (cole) {
            send = cole[row];
        } else {
            int rc = n - row * CHUNK;
            send = rc < 0 ? 0 : (rc > CHUNK ? CHUNK : rc);
        }
        const uint32_t* seg = payload + (size_t)row * CHUNK;
        for (int j = sbeg; j < send; ++j) {
            uint32_t w = seg[j];                 // dense ~109 B span (t-sorted)
            atomicAdd(&hist[w >> 22],            // (c<<8)|tok in bits [22,32)
                      (1ULL << 40) | (unsigned long long)(w & 0x3FFFFFu));
        }
    }
    __syncthreads();

    // writeout: 2048 outputs, each exactly once
    const int tok = threadIdx.x & 255;
    const int cbase = threadIdx.x >> 8;          // 0..1
    #pragma unroll
    for (int k = 0; k < 2; ++k) {
        const int c = cbase + 2 * k;
        const int b = g * GACC + c;
        const unsigned long long v = hist[(c << 8) | tok];
        const float cntf = (float)(uint32_t)(v >> 40);
        const float wts  = (float)(v & ((1ULL << 40) - 1)) * (1.0f / 4194304.0f);
        const int pos = b % 300;
        const int dp = b / 300;
        const int base0 = dp * 153600 + pos;
        out[base0 + tok * 300]         = cntf;   // channel 0: count
        out[base0 + 76800 + tok * 300] = wts;    // channel 1: wt sum
    }
}

// ---- fallback (ws too small / n out of range) ----
__global__ __launch_bounds__(TPB) void e2src_hist_atomic(const float4* __restrict__ x,
                                                         float* __restrict__ out, int n) {
    const float* xf = (const float*)x;
    const float t0 = xf[0];
    const float tlast = xf[(size_t)(n - 1) * 4];
    const float d_wt = tlast - t0 + 1e-4f;
    const float d_dt = tlast - t0 + 1.0f;
    int i = blockIdx.x * blockDim.x + threadIdx.x;
    const int stride = gridDim.x * blockDim.x;
    for (; i < n; i += stride) {
        float4 e = x[i];
        int bucket, tok; float wt;
        classify_full(e, t0, d_wt, d_dt, bucket, tok, wt);
        const int dp = bucket / 300, pos = bucket % 300;
        const int base = dp * 153600 + tok * 300 + pos;
        unsafeAtomicAdd(out + base, 1.0f);
        unsafeAtomicAdd(out + base + 76800, wt);
    }
}

extern "C" void kernel_launch(void* const* d_in, const int* in_sizes, int n_in,
                              void* d_out, int out_size, void* d_ws, size_t ws_size,
                              hipStream_t stream) {
    const float* x = (const float*)d_in[0];
    float* out = (float*)d_out;
    const int n = in_sizes[0] / 4;

    const size_t payload_bytes = (size_t)n * 4u;
    const size_t pfx_bytes = (size_t)B1 * NG * 2u;           // 4,915,200
    const size_t need = payload_bytes + 2u * pfx_bytes;      // 76,939,264 at n=2^24

    if (ws_size < need || n > B1 * CHUNK) {
        hipMemsetAsync(d_out, 0, (size_t)out_size * sizeof(float), stream);
        hipLaunchKernelGGL(e2src_hist_atomic, dim3(8192), dim3(TPB), 0, stream,
                           (const float4*)x, out, n);
        return;
    }

    uint32_t* payload = (uint32_t*)d_ws;
    uint16_t* pfx  = (uint16_t*)((char*)d_ws + payload_bytes);
    uint16_t* pfxT = (uint16_t*)((char*)d_ws + payload_bytes + pfx_bytes);

    hipLaunchKernelGGL(k_bin, dim3(B1), dim3(TPB), 0, stream,
                       (const float4*)x, payload, pfx, n);
    hipLaunchKernelGGL(k_transpose, dim3((NG + 31) / 32, B1 / 32), dim3(256), 0,
                       stream, pfx, pfxT);
    hipLaunchKernelGGL(k_accum, dim3(NG), dim3(ATPB), 0, stream,
                       payload, pfxT, out, n);
    // k_accum writes every output exactly once -> no memset needed.
}

// Round 7
// 502.904 us; speedup vs baseline: 1.1146x; 1.1146x over previous
//
#include <hip/hip_runtime.h>
#include <stdint.h>

// Round 7: make the register stash REAL.
//  Rounds 5/6 post-mortem: VGPR_Count 84/40 proves the 32/16-event stash was
//  spilled to scratch (= the mystery 143-240 MB of global write traffic).
//  Fix: EVT=8 (16 stash VGPRs), CHUNK=2048, B1=8192, no min-wave bound.
//  LDS 17.6 KB -> 8 blocks/CU. Classify once, zero spills.
//  k_accum: GACC=8 (c:3|tok:8|wt_q21 payload), 304 XCD-swizzled blocks.
//
// bucket = (dt*2+p)*300 + pos (2400); group = bucket>>3 (300 groups).
// ws bytes: payload u32*n | pfx u16 [B1][NG] | pfxT u16 [NG][B1] = 76,939,264.

#define TPB 256
#define B1 8192
#define CHUNK 2048                 // B1*CHUNK = 2^24 = n
#define EVT (CHUNK / TPB)          // 8 events per thread
#define NBUCKET 2400
#define SCAN_PER 10                // ceil(NBUCKET/TPB)
#define GACC 8                     // buckets per group
#define NG (NBUCKET / GACC)        // 300 groups
#define ATPB 512                   // k_accum block size

__device__ __forceinline__ void classify_full(const float4 e, const float t0,
                                              const float d_wt, const float d_dt,
                                              int& bucket, int& tok, float& wt) {
    const float c1 = (float)(319.0 / 20.0 + 1e-4);   // W/PW + B
    const float c2 = (float)(239.0 / 15.0 + 1e-4);   // H/PH + B
    const int pos = (int)(floorf(e.y / c1) + floorf(e.z / c2) * 20.0f);
    tok = (int)(floorf(fmodf(e.y, c1)) + floorf(fmodf(e.z, c2)) * 16.0f);
    const int dt = (int)floorf(4.0f * (e.x - t0) / d_dt);
    const int p  = (int)e.w;
    bucket = (dt * 2 + p) * 300 + pos;
    wt = (e.x - t0) / d_wt;
}

__global__ __launch_bounds__(TPB) void k_bin(const float4* __restrict__ x,
                                             uint32_t* __restrict__ payload,
                                             uint16_t* __restrict__ pfx,
                                             int n) {
    __shared__ uint32_t stage[CHUNK];     // 8 KB
    __shared__ uint32_t cnt[NBUCKET];     // 9.6 KB: counts, then cursors
    __shared__ uint32_t wsum[TPB / 64];

    for (int i = threadIdx.x; i < NBUCKET; i += TPB) cnt[i] = 0;
    __syncthreads();

    const float* xf = (const float*)x;
    const float t0 = xf[0];
    const float tlast = xf[(size_t)(n - 1) * 4];
    const float d_wt = tlast - t0 + 1e-4f;
    const float d_dt = tlast - t0 + 1.0f;

    const int beg = blockIdx.x * CHUNK;
    const bool full = (beg + CHUNK <= n);

    // phase 1: classify once, stash (8 pk + 8 bk = 16 VGPRs), count
    uint32_t pk[EVT];
    uint32_t bk[EVT];
    if (full) {
        #pragma unroll
        for (int k = 0; k < EVT; ++k) {
            float4 e = x[beg + threadIdx.x + k * TPB];
            int bucket, tok; float wt;
            classify_full(e, t0, d_wt, d_dt, bucket, tok, wt);
            uint32_t q = (uint32_t)(wt * 2097152.0f);          // q21
            q = q > 2097151u ? 2097151u : q;
            pk[k] = ((uint32_t)(bucket & 7) << 29) | ((uint32_t)tok << 21) | q;
            bk[k] = (uint32_t)bucket;
            atomicAdd(&cnt[bucket], 1u);
        }
    } else {
        #pragma unroll
        for (int k = 0; k < EVT; ++k) {
            const int i = beg + threadIdx.x + k * TPB;
            if (i < n) {
                float4 e = x[i];
                int bucket, tok; float wt;
                classify_full(e, t0, d_wt, d_dt, bucket, tok, wt);
                uint32_t q = (uint32_t)(wt * 2097152.0f);
                q = q > 2097151u ? 2097151u : q;
                pk[k] = ((uint32_t)(bucket & 7) << 29) | ((uint32_t)tok << 21) | q;
                bk[k] = (uint32_t)bucket;
                atomicAdd(&cnt[bucket], 1u);
            } else {
                bk[k] = 0xFFFFFFFFu;
            }
        }
    }
    __syncthreads();

    // phase 2: block-local exclusive scan of NBUCKET counts
    uint32_t v[SCAN_PER];
    uint32_t sum = 0;
    const int base_i = threadIdx.x * SCAN_PER;
    #pragma unroll
    for (int j = 0; j < SCAN_PER; ++j) {
        int idx = base_i + j;
        uint32_t c = (idx < NBUCKET) ? cnt[idx] : 0u;
        v[j] = sum;
        sum += c;
    }
    uint32_t inc = sum;
    #pragma unroll
    for (int off = 1; off < 64; off <<= 1) {
        uint32_t u = __shfl_up(inc, off, 64);
        if ((threadIdx.x & 63) >= off) inc += u;
    }
    const int wid = threadIdx.x >> 6, lid = threadIdx.x & 63;
    if (lid == 63) wsum[wid] = inc;
    __syncthreads();
    uint32_t woff = 0;
    for (int w = 0; w < wid; ++w) woff += wsum[w];
    const uint32_t excl = woff + inc - sum;

    uint16_t* prow = pfx + (size_t)blockIdx.x * NG;
    #pragma unroll
    for (int j = 0; j < SCAN_PER; ++j) {
        int idx = base_i + j;
        if (idx < NBUCKET) {
            uint32_t p = excl + v[j];
            cnt[idx] = p;                       // cursor for the sort
            if ((idx & 7) == 0) prow[idx >> 3] = (uint16_t)p;   // group start
        }
    }
    __syncthreads();

    // phase 3: replay from registers -> rank -> LDS stage
    if (full) {
        #pragma unroll
        for (int k = 0; k < EVT; ++k) {
            uint32_t rank = atomicAdd(&cnt[bk[k]], 1u);
            stage[rank] = pk[k];
        }
    } else {
        #pragma unroll
        for (int k = 0; k < EVT; ++k) {
            if (bk[k] != 0xFFFFFFFFu) {
                uint32_t rank = atomicAdd(&cnt[bk[k]], 1u);
                stage[rank] = pk[k];
            }
        }
    }
    __syncthreads();

    // phase 4: coalesced LDS -> global writeout (complete lines only)
    const int end = min(beg + CHUNK, n);
    const int cntE = end - beg;
    uint32_t* pbase = payload + (size_t)blockIdx.x * CHUNK;
    const int n4 = cntE >> 2;
    const uint4* s4 = (const uint4*)stage;
    uint4* g4 = (uint4*)pbase;
    for (int i = threadIdx.x; i < n4; i += TPB) g4[i] = s4[i];
    for (int i = (n4 << 2) + threadIdx.x; i < cntE; i += TPB) pbase[i] = stage[i];
}

// pfx [B1][NG] u16 -> pfxT [NG][B1] u16 (coalesced offset reads in k_accum)
__global__ __launch_bounds__(256) void k_transpose(const uint16_t* __restrict__ in,
                                                   uint16_t* __restrict__ out) {
    __shared__ uint16_t tile[32][33];
    const int c0 = blockIdx.x * 32;    // NG cols: 10 tiles (guarded, 300 not /32)
    const int r0 = blockIdx.y * 32;    // B1 rows: 256 tiles
    const int tx = threadIdx.x & 31;
    const int ty = threadIdx.x >> 5;   // 0..7
    for (int j = ty; j < 32; j += 8)
        if (c0 + tx < NG)
            tile[j][tx] = in[(size_t)(r0 + j) * NG + (c0 + tx)];
    __syncthreads();
    for (int j = ty; j < 32; j += 8)
        if (c0 + j < NG)
            out[(size_t)(c0 + j) * B1 + (r0 + tx)] = tile[tx][j];
}

// One block per 8-bucket group, XCD-swizzled: g = (b&7)*38 + (b>>3) so XCD k
// owns ~38 adjacent groups (boundary payload/pfx lines stay in one XCD L2).
// 304 blocks; 4 with g >= 300 exit immediately.
__global__ __launch_bounds__(ATPB) void k_accum(const uint32_t* __restrict__ payload,
                                                const uint16_t* __restrict__ pfxT,
                                                float* __restrict__ out,
                                                int n) {
    const int g = (blockIdx.x & 7) * 38 + (blockIdx.x >> 3);
    if (g >= NG) return;               // uniform early-exit, before any barrier

    __shared__ unsigned long long hist[GACC * 256];   // (c,tok) -> cnt<<40 | q21sum
    for (int i = threadIdx.x; i < GACC * 256; i += ATPB) hist[i] = 0ULL;
    __syncthreads();

    const uint16_t* colb = pfxT + (size_t)g * B1;
    const uint16_t* cole = (g + 1 < NG) ? (pfxT + (size_t)(g + 1) * B1) : nullptr;

    for (int row = threadIdx.x; row < B1; row += ATPB) {
        const int sbeg = colb[row];
        int send;
        if (cole) {
            send = cole[row];
        } else {
            int rc = n - row * CHUNK;
            send = rc < 0 ? 0 : (rc > CHUNK ? CHUNK : rc);
        }
        const uint32_t* seg = payload + (size_t)row * CHUNK;
        for (int j = sbeg; j < send; ++j) {
            uint32_t w = seg[j];                 // dense span (t-sorted chunks)
            atomicAdd(&hist[w >> 21],            // (c<<8)|tok in bits [21,32)
                      (1ULL << 40) | (unsigned long long)(w & 0x1FFFFFu));
        }
    }
    __syncthreads();

    // writeout: 2048 hist entries -> 4096 outputs, each exactly once
    for (int i = threadIdx.x; i < GACC * 256; i += ATPB) {
        const int c = i >> 8;
        const int tok = i & 255;
        const int b = g * GACC + c;
        const unsigned long long v = hist[i];
        const float cntf = (float)(uint32_t)(v >> 40);
        const float wts  = (float)(v & ((1ULL << 40) - 1)) * (1.0f / 2097152.0f);
        const int pos = b % 300;
        const int dp = b / 300;
        const int base0 = dp * 153600 + pos;
        out[base0 + tok * 300]         = cntf;   // channel 0: count
        out[base0 + 76800 + tok * 300] = wts;    // channel 1: wt sum
    }
}

// ---- fallback (ws too small / n out of range) ----
__global__ __launch_bounds__(TPB) void e2src_hist_atomic(const float4* __restrict__ x,
                                                         float* __restrict__ out, int n) {
    const float* xf = (const float*)x;
    const float t0 = xf[0];
    const float tlast = xf[(size_t)(n - 1) * 4];
    const float d_wt = tlast - t0 + 1e-4f;
    const float d_dt = tlast - t0 + 1.0f;
    int i = blockIdx.x * blockDim.x + threadIdx.x;
    const int stride = gridDim.x * blockDim.x;
    for (; i < n; i += stride) {
        float4 e = x[i];
        int bucket, tok; float wt;
        classify_full(e, t0, d_wt, d_dt, bucket, tok, wt);
        const int dp = bucket / 300, pos = bucket % 300;
        const int base = dp * 153600 + tok * 300 + pos;
        unsafeAtomicAdd(out + base, 1.0f);
        unsafeAtomicAdd(out + base + 76800, wt);
    }
}

extern "C" void kernel_launch(void* const* d_in, const int* in_sizes, int n_in,
                              void* d_out, int out_size, void* d_ws, size_t ws_size,
                              hipStream_t stream) {
    const float* x = (const float*)d_in[0];
    float* out = (float*)d_out;
    const int n = in_sizes[0] / 4;

    const size_t payload_bytes = (size_t)n * 4u;
    const size_t pfx_bytes = (size_t)B1 * NG * 2u;           // 4,915,200
    const size_t need = payload_bytes + 2u * pfx_bytes;      // 76,939,264 at n=2^24

    if (ws_size < need || n > B1 * CHUNK) {
        hipMemsetAsync(d_out, 0, (size_t)out_size * sizeof(float), stream);
        hipLaunchKernelGGL(e2src_hist_atomic, dim3(8192), dim3(TPB), 0, stream,
                           (const float4*)x, out, n);
        return;
    }

    uint32_t* payload = (uint32_t*)d_ws;
    uint16_t* pfx  = (uint16_t*)((char*)d_ws + payload_bytes);
    uint16_t* pfxT = (uint16_t*)((char*)d_ws + payload_bytes + pfx_bytes);

    hipLaunchKernelGGL(k_bin, dim3(B1), dim3(TPB), 0, stream,
                       (const float4*)x, payload, pfx, n);
    hipLaunchKernelGGL(k_transpose, dim3((NG + 31) / 32, B1 / 32), dim3(256), 0,
                       stream, pfx, pfxT);
    hipLaunchKernelGGL(k_accum, dim3(304), dim3(ATPB), 0, stream,
                       payload, pfxT, out, n);
    // k_accum writes every output exactly once -> no memset needed.
}